// Round 15
// baseline (299.759 us; speedup 1.0000x reference)
//
#include <hip/hip_runtime.h>
#include <math.h>

// N=20000 nodes, E=320000 edges (+N self loops), H=4 heads, HID=128, HC=512
#define NEG 0.2f
#define BN_EPS 1e-5f
#define LOG2E 1.44269504088896340736f

typedef __attribute__((ext_vector_type(8))) short  bf16x8;
typedef __attribute__((ext_vector_type(4))) float  f32x4;

__device__ inline unsigned short f2b(float f) {
    unsigned int u = __float_as_uint(f);
    unsigned int r = (u + 0x7fffu + ((u >> 16) & 1u)) >> 16;
    return (unsigned short)r;
}
__device__ inline float b2f_lo(unsigned int u) { return __uint_as_float(u << 16); }
__device__ inline float b2f_hi(unsigned int u) { return __uint_as_float(u & 0xffff0000u); }

__device__ inline unsigned int cvt_pk_bf16(float lo, float hi) {
    unsigned int r;
    asm("v_cvt_pk_bf16_f32 %0, %1, %2" : "=v"(r) : "v"(lo), "v"(hi));
    return r;
}

template<int CTRL>
__device__ inline float dpp_add(float x) {
    int y = __builtin_amdgcn_update_dpp(0, __float_as_int(x), CTRL, 0xF, 0xF, true);
    return x + __int_as_float(y);
}

// ---------------- CSR build ----------------
// per-block (1024) local exclusive scan of (counts[i]+1) + block totals
__global__ void pscan_kernel(const int* __restrict__ counts, int* __restrict__ offsets,
                             int* __restrict__ btot, int n) {
    __shared__ int wsums[16];
    int tid = threadIdx.x, wid = tid >> 6, lane = tid & 63;
    int i = blockIdx.x * 1024 + tid;
    int v = (i < n) ? counts[i] + 1 : 0;   // +1 = self loop
    int incl = v;
#pragma unroll
    for (int off = 1; off < 64; off <<= 1) {
        int t = __shfl_up(incl, off);
        if (lane >= off) incl += t;
    }
    if (lane == 63) wsums[wid] = incl;
    __syncthreads();
    if (tid < 16) {
        int wv = wsums[tid];
        int winc = wv;
#pragma unroll
        for (int off = 1; off < 16; off <<= 1) {
            int t = __shfl_up(winc, off);
            if (tid >= off) winc += t;
        }
        wsums[tid] = winc - wv;
        if (tid == 15) btot[blockIdx.x] = winc;
    }
    __syncthreads();
    if (i < n) offsets[i] = wsums[wid] + incl - v;
}

__global__ void addb_kernel(int* __restrict__ offsets, const int* __restrict__ btot,
                            int n, int nb) {
    __shared__ int sbase;
    if (threadIdx.x == 0) {
        int b = 0, t = 0;
        for (int j = 0; j < nb; ++j) {
            int v = btot[j];
            if (j < (int)blockIdx.x) b += v;
            t += v;
        }
        sbase = b;
        if (blockIdx.x == (unsigned)(nb - 1)) offsets[n] = t;
    }
    __syncthreads();
    int i = blockIdx.x * 1024 + threadIdx.x;
    if (i < n) offsets[i] += sbase;
}

__global__ void scatter_kernel(const int* __restrict__ src, const int* __restrict__ dst,
                               const int* __restrict__ offsets, int* __restrict__ cursor,
                               int* __restrict__ csr_src, int E, int N) {
    int i = blockIdx.x * 256 + threadIdx.x;
    if (i < E) {
        int d = dst[i];
        int pos = offsets[d] + 1 + atomicAdd(&cursor[d], 1);
        csr_src[pos] = src[i];
    } else if (i < E + N) {
        int n = i - E;
        csr_src[offsets[n]] = n;   // self loop at slot 0
    }
}

// ---------------- fused prep: hist + x->B-frag bf16, 5 W^T frag packs, bias concat ----------------
__device__ inline void pack_body(const float* __restrict__ W, unsigned short* __restrict__ Ap,
                                 int K, int Nsrc, int fn_off, int t) {
    int KS = K >> 5;
    int lane = t & 63;
    int frag = t >> 6;
    int ks = frag % KS;
    int nb = frag / KS;
    int fn = fn_off + nb;
    int k0 = ks * 32 + (lane >> 4) * 8;
    int col = nb * 16 + (lane & 15);
    unsigned short o[8];
#pragma unroll
    for (int j = 0; j < 8; ++j) o[j] = f2b(W[(size_t)(k0 + j) * Nsrc + col]);
    *(uint4*)&Ap[(((size_t)fn * KS + ks) * 64 + lane) * 8] = *(uint4*)o;
}

__global__ void prep_kernel(const float* __restrict__ x, unsigned short* __restrict__ xbf,
                            const int* __restrict__ dst, int* __restrict__ counts, int E4,
                            const float* __restrict__ Wl0, const float* __restrict__ Wr0,
                            const float* __restrict__ skW, const float* __restrict__ Wl1,
                            const float* __restrict__ Wr1,
                            unsigned short* __restrict__ Ap0, unsigned short* __restrict__ Ap1,
                            const float* __restrict__ bl0, const float* __restrict__ br0,
                            const float* __restrict__ skb, const float* __restrict__ bl1,
                            const float* __restrict__ br1,
                            float* __restrict__ bias0f, float* __restrict__ bias1f, int N) {
    const int CONV = (N / 16) * 8 / 4;     // 2500 blocks: x -> B-frag layout (K=256, KS=8)
    int b = blockIdx.x, tid = threadIdx.x;
    int wid = tid >> 6, lane = tid & 63;
    if (b < CONV) {
        int wt = b * 4 + wid;              // (ntile, ks)
        int ntile = wt >> 3, ks = wt & 7;
        int r = ntile * 16 + (lane & 15);
        int k = ks * 32 + (lane >> 4) * 8;
        const float4* p = (const float4*)&x[(size_t)r * 256 + k];
        float4 a = p[0], c = p[1];
        unsigned short o[8];
        o[0] = f2b(a.x); o[1] = f2b(a.y); o[2] = f2b(a.z); o[3] = f2b(a.w);
        o[4] = f2b(c.x); o[5] = f2b(c.y); o[6] = f2b(c.z); o[7] = f2b(c.w);
        *(uint4*)&xbf[(((size_t)ntile * 8 + ks) * 64 + lane) * 8] = *(uint4*)o;
        return;
    }
    b -= CONV;
    if (b < 313) {                          // hist (int4-vectorized)
        int i = b * 256 + tid;
        if (i < E4) {
            int4 d = ((const int4*)dst)[i];
            atomicAdd(&counts[d.x], 1);
            atomicAdd(&counts[d.y], 1);
            atomicAdd(&counts[d.z], 1);
            atomicAdd(&counts[d.w], 1);
        }
        return;
    }
    b -= 313;
    if (b < 64)  { pack_body(Wl0, Ap0, 256, 512, 0,  b * 256 + tid); return; }
    b -= 64;
    if (b < 64)  { pack_body(Wr0, Ap0, 256, 512, 32, b * 256 + tid); return; }
    b -= 64;
    if (b < 16)  { pack_body(skW, Ap0, 256, 128, 64, b * 256 + tid); return; }
    b -= 16;
    if (b < 32)  { pack_body(Wl1, Ap1, 128, 512, 0,  b * 256 + tid); return; }
    b -= 32;
    if (b < 32)  { pack_body(Wr1, Ap1, 128, 512, 32, b * 256 + tid); return; }
    b -= 32;
    {
        int i = b * 256 + tid;
        if (i < 1152) {
            float v = (i < 512) ? bl0[i] : (i < 1024 ? br0[i - 512] : skb[i - 1024]);
            bias0f[i] = v;
        } else if (i < 1152 + 1024) {
            int j = i - 1152;
            bias1f[j] = (j < 512) ? bl1[j] : br1[j - 512];
        }
    }
}

// ---------------- transposed MFMA GEMM with LDS-staged B ----------------
// A = W^T frags (Ap, direct global), B = node-feature frags staged once per block
// through LDS (16 frags = 16KB per k-step; waves 0,1 and 2,3 share node windows).
__global__ __launch_bounds__(256) void gemm_nt(
    const unsigned short* __restrict__ Bf, const unsigned short* __restrict__ Ap,
    const float* __restrict__ bias, unsigned short* __restrict__ out,
    int Mnodes, int Ncols, int K) {
    __shared__ unsigned short Bs[16 * 64 * 8];   // 16KB
    int wid = threadIdx.x >> 6, lane = threadIdx.x & 63;
    int g = lane >> 4, c15 = lane & 15;
    int cfbase = blockIdx.y * 8 + (wid & 1) * 4;            // ch-frag base (4 frags = 64 ch)
    int ch0 = cfbase * 16;
    int nodeBase = blockIdx.x * 256 + (wid >> 1) * 128;     // wave node window (128)
    const int KS = K >> 5;
    const int lastNT = (Mnodes - 1) >> 4;
    const int baseTile = blockIdx.x * 16;

    f32x4 acc[4][8];
#pragma unroll
    for (int i = 0; i < 4; ++i)
#pragma unroll
        for (int j = 0; j < 8; ++j) acc[i][j] = (f32x4){0.f, 0.f, 0.f, 0.f};

    // staging tile ids: this wave (as "group") loads q = wid, wid+4, wid+8, wid+12
    int stq[4];
#pragma unroll
    for (int s = 0; s < 4; ++s) {
        int t = baseTile + wid + s * 4;
        stq[s] = t < lastNT ? t : lastNT;
    }
    int nd[8];
#pragma unroll
    for (int nf = 0; nf < 8; ++nf) nd[nf] = nodeBase + nf * 16 + c15;
    int qbase = (wid >> 1) * 8;   // this wave's B window inside Bs

    for (int ks = 0; ks < KS; ++ks) {
        __syncthreads();   // previous compute done before overwrite
#pragma unroll
        for (int s = 0; s < 4; ++s) {
            int q = wid + s * 4;
            *(uint4*)&Bs[((size_t)(q * 64 + lane)) * 8] =
                *(const uint4*)&Bf[(((size_t)stq[s] * KS + ks) * 64 + lane) * 8];
        }
        __syncthreads();
        bf16x8 a[4];
#pragma unroll
        for (int mf = 0; mf < 4; ++mf)
            a[mf] = *(const bf16x8*)&Ap[(((size_t)(cfbase + mf) * KS + ks) * 64 + lane) * 8];
        bf16x8 b[8];
#pragma unroll
        for (int nf = 0; nf < 8; ++nf)
            b[nf] = *(const bf16x8*)&Bs[((size_t)((qbase + nf) * 64 + lane)) * 8];
#pragma unroll
        for (int nf = 0; nf < 8; ++nf)
#pragma unroll
            for (int mf = 0; mf < 4; ++mf)
                acc[mf][nf] = __builtin_amdgcn_mfma_f32_16x16x32_bf16(a[mf], b[nf], acc[mf][nf], 0, 0, 0);
    }
    // epilogue: D row = ch (4 consecutive per lane), col = node
#pragma unroll
    for (int mf = 0; mf < 4; ++mf) {
        int ch = ch0 + mf * 16 + g * 4;
        float4 bs = *(const float4*)&bias[ch];
#pragma unroll
        for (int nf = 0; nf < 8; ++nf) {
            f32x4 v = acc[mf][nf];
            unsigned int p0 = cvt_pk_bf16(v[0] + bs.x, v[1] + bs.y);
            unsigned int p1 = cvt_pk_bf16(v[2] + bs.z, v[3] + bs.w);
            if (nd[nf] < Mnodes)
                *(uint2*)&out[(size_t)nd[nf] * Ncols + ch] = make_uint2(p0, p1);
        }
    }
}

// ---------------- fused edge score + online softmax + aggregate (bf16 features) ----------------
// 1 wave = 1 node = 1 block; depth-8 prefetch; scalarized gather addressing (saddr form);
// DPP reduce; exp2 domain; bf16 prebn out
__global__ __launch_bounds__(64) void gat_edge_kernel(
    const int* __restrict__ offsets, const int* __restrict__ csr_src,
    const unsigned short* __restrict__ base, int stride,
    const float* __restrict__ att, const float* __restrict__ bvec,
    unsigned short* __restrict__ prebn, int N) {
    int lane = threadIdx.x;
    int n = blockIdx.x;
    if (n >= N) return;
    int start = offsets[n], e1 = offsets[n + 1] - 1;
    float xrv[8], ca[8], cb[8], bv[8];
    {
        uint4 u = *(const uint4*)&base[(size_t)n * stride + 512 + lane * 8];
        xrv[0] = b2f_lo(u.x); xrv[1] = b2f_hi(u.x);
        xrv[2] = b2f_lo(u.y); xrv[3] = b2f_hi(u.y);
        xrv[4] = b2f_lo(u.z); xrv[5] = b2f_hi(u.z);
        xrv[6] = b2f_lo(u.w); xrv[7] = b2f_hi(u.w);
        const float4* q = (const float4*)&att[lane * 8];
        float4 u0 = q[0], u1 = q[1];
        // att*leaky(t) = 0.6*att*t + 0.4*att*|t|, pre-scaled by log2(e) for exp2 softmax
        const float sA = 0.6f * LOG2E, sB = 0.4f * LOG2E;
        ca[0] = u0.x * sA; ca[1] = u0.y * sA; ca[2] = u0.z * sA; ca[3] = u0.w * sA;
        ca[4] = u1.x * sA; ca[5] = u1.y * sA; ca[6] = u1.z * sA; ca[7] = u1.w * sA;
        cb[0] = u0.x * sB; cb[1] = u0.y * sB; cb[2] = u0.z * sB; cb[3] = u0.w * sB;
        cb[4] = u1.x * sB; cb[5] = u1.y * sB; cb[6] = u1.z * sB; cb[7] = u1.w * sB;
        if (lane < 16) {
            const float4* bp = (const float4*)&bvec[lane * 8];
            float4 b0 = bp[0], b1 = bp[1];
            bv[0] = b0.x; bv[1] = b0.y; bv[2] = b0.z; bv[3] = b0.w;
            bv[4] = b1.x; bv[5] = b1.y; bv[6] = b1.z; bv[7] = b1.w;
        }
    }
    float m = -INFINITY, d = 0.f;
    float acc[8] = {0, 0, 0, 0, 0, 0, 0, 0};

    const int lofs = lane * 8;
    auto LD = [&](int j) -> uint4 {
        int jj = j < e1 ? j : e1;
        int s = __builtin_amdgcn_readfirstlane(csr_src[jj]);
        const unsigned short* rowp = base + (size_t)s * stride;
        return *(const uint4*)(rowp + lofs);
    };
    auto PROC = [&](const uint4& Q) {
        float v[8];
        v[0] = b2f_lo(Q.x); v[1] = b2f_hi(Q.x);
        v[2] = b2f_lo(Q.y); v[3] = b2f_hi(Q.y);
        v[4] = b2f_lo(Q.z); v[5] = b2f_hi(Q.z);
        v[6] = b2f_lo(Q.w); v[7] = b2f_hi(Q.w);
        float p = 0.f;
#pragma unroll
        for (int j = 0; j < 8; ++j) {
            float t = v[j] + xrv[j];
            p = fmaf(ca[j], t, fmaf(cb[j], fabsf(t), p));
        }
        p = dpp_add<0xB1>(p);    // quad_perm xor1
        p = dpp_add<0x4E>(p);    // quad_perm xor2
        p = dpp_add<0x141>(p);   // row_half_mirror
        p = dpp_add<0x140>(p);   // row_mirror -> 16-lane sum
        if (__any(p > m)) {
            float mn = fmaxf(m, p);
            float sc = exp2f(m - mn);
            float w = exp2f(p - mn);
            d = fmaf(d, sc, w);
#pragma unroll
            for (int j = 0; j < 8; ++j) acc[j] = fmaf(w, v[j], acc[j] * sc);
            m = mn;
        } else {
            float w = exp2f(p - m);
            d += w;
#pragma unroll
            for (int j = 0; j < 8; ++j) acc[j] = fmaf(w, v[j], acc[j]);
        }
    };

    uint4 q0 = LD(start),     q1 = LD(start + 1), q2 = LD(start + 2), q3 = LD(start + 3),
          q4 = LD(start + 4), q5 = LD(start + 5), q6 = LD(start + 6), q7 = LD(start + 7);
    int i = start;
    for (;;) {
        PROC(q0); if (++i > e1) break; q0 = LD(i + 7);
        PROC(q1); if (++i > e1) break; q1 = LD(i + 7);
        PROC(q2); if (++i > e1) break; q2 = LD(i + 7);
        PROC(q3); if (++i > e1) break; q3 = LD(i + 7);
        PROC(q4); if (++i > e1) break; q4 = LD(i + 7);
        PROC(q5); if (++i > e1) break; q5 = LD(i + 7);
        PROC(q6); if (++i > e1) break; q6 = LD(i + 7);
        PROC(q7); if (++i > e1) break; q7 = LD(i + 7);
    }

    float inv = 1.f / d;
    float t[8];
#pragma unroll
    for (int j = 0; j < 8; ++j) {
        float u = acc[j] * inv;
        u += __shfl_xor(u, 16);    // sum over heads (h bit0)
        u += __shfl_xor(u, 32);    // (h bit1)
        t[j] = u;
    }
    if (lane < 16) {
        float o[8];
#pragma unroll
        for (int j = 0; j < 8; ++j) {
            float v2 = 0.25f * t[j] + bv[j];
            o[j] = v2 > 0.f ? v2 : NEG * v2;   // leaky_relu before BN
        }
        uint4 pk;
        pk.x = cvt_pk_bf16(o[0], o[1]);
        pk.y = cvt_pk_bf16(o[2], o[3]);
        pk.z = cvt_pk_bf16(o[4], o[5]);
        pk.w = cvt_pk_bf16(o[6], o[7]);
        *(uint4*)&prebn[(size_t)n * 128 + lane * 8] = pk;
    }
}

// ---------------- BN stats + apply (bf16 prebn input) ----------------
__global__ void bn_stats_kernel(const unsigned short* __restrict__ v,
                                float* __restrict__ stats, int N) {
    int c = threadIdx.x;  // 128
    int r0 = blockIdx.x * 40;
    int r1 = r0 + 40; if (r1 > N) r1 = N;
    float s = 0.f, ss = 0.f;
    for (int r = r0; r < r1; ++r) {
        float x = b2f_lo((unsigned int)v[(size_t)r * 128 + c]);
        s += x; ss += x * x;
    }
    atomicAdd(&stats[c], s);
    atomicAdd(&stats[128 + c], ss);
}

// layer0 BN apply: write bf16 B-frag layout (feeds gemm1), add strided bf16 skip
__global__ void bn_apply_frag_kernel(const unsigned short* __restrict__ v,
                                     const float* __restrict__ stats,
                                     const float* __restrict__ g, const float* __restrict__ be,
                                     const unsigned short* __restrict__ skip16, int skipStride,
                                     unsigned short* __restrict__ outf, int N) {
    int wid = threadIdx.x >> 6, lane = threadIdx.x & 63;
    int wt = blockIdx.x * 4 + wid;
    int ntile = wt >> 2, ks = wt & 3;
    int r = ntile * 16 + (lane & 15);
    if (r >= N) return;
    int c = ks * 32 + (lane >> 4) * 8;
    float invN = 1.f / (float)N;
    float4 s0 = *(const float4*)&stats[c],       s1 = *(const float4*)&stats[c + 4];
    float4 q0 = *(const float4*)&stats[128 + c], q1 = *(const float4*)&stats[128 + c + 4];
    float4 g0 = *(const float4*)&g[c],  g1 = *(const float4*)&g[c + 4];
    float4 e0 = *(const float4*)&be[c], e1 = *(const float4*)&be[c + 4];
    float mu[8]   = {s0.x, s0.y, s0.z, s0.w, s1.x, s1.y, s1.z, s1.w};
    float ssum[8] = {q0.x, q0.y, q0.z, q0.w, q1.x, q1.y, q1.z, q1.w};
    float gg[8]   = {g0.x, g0.y, g0.z, g0.w, g1.x, g1.y, g1.z, g1.w};
    float ee[8]   = {e0.x, e0.y, e0.z, e0.w, e1.x, e1.y, e1.z, e1.w};
    uint4 xu = *(const uint4*)&v[(size_t)r * 128 + c];
    float xv[8] = {b2f_lo(xu.x), b2f_hi(xu.x), b2f_lo(xu.y), b2f_hi(xu.y),
                   b2f_lo(xu.z), b2f_hi(xu.z), b2f_lo(xu.w), b2f_hi(xu.w)};
    uint4 sk = *(const uint4*)&skip16[(size_t)r * skipStride + c];
    float skf[8] = {b2f_lo(sk.x), b2f_hi(sk.x), b2f_lo(sk.y), b2f_hi(sk.y),
                    b2f_lo(sk.z), b2f_hi(sk.z), b2f_lo(sk.w), b2f_hi(sk.w)};
    unsigned short o[8];
#pragma unroll
    for (int j = 0; j < 8; ++j) {
        float muj = mu[j] * invN;
        float var = ssum[j] * invN - muj * muj;
        float rs = rsqrtf(var + BN_EPS);
        o[j] = f2b((xv[j] - muj) * rs * gg[j] + ee[j] + skf[j]);
    }
    *(uint4*)&outf[(((size_t)ntile * 4 + ks) * 64 + lane) * 8] = *(uint4*)o;
}

// layer1: f32 row-major to d_out
__global__ void bn_apply1_kernel(const unsigned short* __restrict__ v,
                                 const float* __restrict__ stats,
                                 const float* __restrict__ g, const float* __restrict__ be,
                                 float* __restrict__ outf, int N) {
    int t = blockIdx.x * 256 + threadIdx.x;
    if (t >= N * 16) return;
    int node = t >> 4, c = (t & 15) * 8;
    float invN = 1.f / (float)N;
    uint4 xu = *(const uint4*)&v[(size_t)node * 128 + c];
    float xv[8] = {b2f_lo(xu.x), b2f_hi(xu.x), b2f_lo(xu.y), b2f_hi(xu.y),
                   b2f_lo(xu.z), b2f_hi(xu.z), b2f_lo(xu.w), b2f_hi(xu.w)};
    float4 s0 = *(const float4*)&stats[c],       s1 = *(const float4*)&stats[c + 4];
    float4 q0 = *(const float4*)&stats[128 + c], q1 = *(const float4*)&stats[128 + c + 4];
    float4 g0 = *(const float4*)&g[c],  g1 = *(const float4*)&g[c + 4];
    float4 e0 = *(const float4*)&be[c], e1 = *(const float4*)&be[c + 4];
    float mu[8]   = {s0.x, s0.y, s0.z, s0.w, s1.x, s1.y, s1.z, s1.w};
    float ssum[8] = {q0.x, q0.y, q0.z, q0.w, q1.x, q1.y, q1.z, q1.w};
    float gg[8]   = {g0.x, g0.y, g0.z, g0.w, g1.x, g1.y, g1.z, g1.w};
    float ee[8]   = {e0.x, e0.y, e0.z, e0.w, e1.x, e1.y, e1.z, e1.w};
    float o[8];
#pragma unroll
    for (int j = 0; j < 8; ++j) {
        float muj = mu[j] * invN;
        float var = ssum[j] * invN - muj * muj;
        float rs = rsqrtf(var + BN_EPS);
        o[j] = (xv[j] - muj) * rs * gg[j] + ee[j];
    }
    float4* op = (float4*)&outf[(size_t)node * 128 + c];
    op[0] = make_float4(o[0], o[1], o[2], o[3]);
    op[1] = make_float4(o[4], o[5], o[6], o[7]);
}

// ---------------- host ----------------
extern "C" void kernel_launch(void* const* d_in, const int* in_sizes, int n_in,
                              void* d_out, int out_size, void* d_ws, size_t ws_size,
                              hipStream_t stream) {
    const float* x    = (const float*)d_in[0];
    const int*   ei   = (const int*)d_in[1];
    const float* Wl0  = (const float*)d_in[2];
    const float* Wr0  = (const float*)d_in[3];
    const float* bl0  = (const float*)d_in[4];
    const float* br0  = (const float*)d_in[5];
    const float* att0 = (const float*)d_in[6];
    const float* b0   = (const float*)d_in[7];
    const float* g0   = (const float*)d_in[8];
    const float* be0  = (const float*)d_in[9];
    const float* Wl1  = (const float*)d_in[10];
    const float* Wr1  = (const float*)d_in[11];
    const float* bl1  = (const float*)d_in[12];
    const float* br1  = (const float*)d_in[13];
    const float* att1 = (const float*)d_in[14];
    const float* b1   = (const float*)d_in[15];
    const float* g1   = (const float*)d_in[16];
    const float* be1  = (const float*)d_in[17];
    const float* skW  = (const float*)d_in[18];
    const float* skb  = (const float*)d_in[19];

    const int K0 = 256, K1 = 128;
    int N = in_sizes[0] / K0;   // 20000
    int E = in_sizes[1] / 2;    // 320000
    int Etot = E + N;
    int NB = (N + 1023) / 1024; // scan blocks (20)

    // workspace layout (counts|cursor|stats contiguous for one memset)
    char* ws = (char*)d_ws;
    size_t off = 0;
    auto alloc = [&](size_t bytes) { size_t r = off; off += (bytes + 255) & ~(size_t)255; return r; };
    size_t z0 = off;
    int*   counts  = (int*)(ws + alloc((size_t)N * 4));
    int*   cursor  = (int*)(ws + alloc((size_t)N * 4));
    float* stats   = (float*)(ws + alloc(512 * 4));
    size_t z1 = off;
    int*   offsets = (int*)(ws + alloc((size_t)(N + 1) * 4));
    int*   csr_src = (int*)(ws + alloc((size_t)Etot * 4));
    int*   btot    = (int*)(ws + alloc((size_t)NB * 4));
    unsigned short* xbf   = (unsigned short*)(ws + alloc((size_t)N * 256 * 2));   // B-frag layout
    unsigned short* l0f   = (unsigned short*)(ws + alloc((size_t)N * 128 * 2));   // B-frag layout
    unsigned short* prebn = (unsigned short*)(ws + alloc((size_t)N * 128 * 2));   // bf16
    unsigned short* fused0 = (unsigned short*)(ws + alloc((size_t)N * 1152 * 2)); // [xl|xr|skip]
    unsigned short* fused1 = fused0;                                              // alias
    unsigned short* Ap0 = (unsigned short*)(ws + alloc((size_t)(1152 / 16) * (K0 / 32) * 64 * 8 * 2));
    unsigned short* Ap1 = (unsigned short*)(ws + alloc((size_t)(1024 / 16) * (K1 / 32) * 64 * 8 * 2));
    float* bias0f = (float*)(ws + alloc(1152 * 4));
    float* bias1f = (float*)(ws + alloc(1024 * 4));
    float* outf = (float*)d_out;

    const int* src = ei;        // edge_index[0]
    const int* dst = ei + E;    // edge_index[1]

    // zero counts/cursor/stats in one shot
    hipMemsetAsync(ws + z0, 0, z1 - z0, stream);

    // fused prep: conv(B-frag) + hist + 5 packs + bias concat
    {
        int CONV = (N / 16) * 8 / 4;   // 2500
        int nblk = CONV + 313 + 64 + 64 + 16 + 32 + 32 + 9;
        prep_kernel<<<nblk, 256, 0, stream>>>(x, xbf, dst, counts, E / 4,
                                              Wl0, Wr0, skW, Wl1, Wr1, Ap0, Ap1,
                                              bl0, br0, skb, bl1, br1, bias0f, bias1f, N);
    }
    // CSR build (scan depends on hist inside prep)
    pscan_kernel<<<NB, 1024, 0, stream>>>(counts, offsets, btot, N);
    addb_kernel<<<NB, 1024, 0, stream>>>(offsets, btot, N, NB);
    scatter_kernel<<<(Etot + 255) / 256, 256, 0, stream>>>(src, dst, offsets, cursor, csr_src, E, N);

    // layer0: one fused transposed GEMM  [xl | xr | skip]
    {
        dim3 g((N + 255) / 256, 1152 / 128);
        gemm_nt<<<g, 256, 0, stream>>>(xbf, Ap0, bias0f, fused0, N, 1152, K0);
    }
    gat_edge_kernel<<<N, 64, 0, stream>>>(offsets, csr_src, fused0, 1152, att0, b0, prebn, N);
    bn_stats_kernel<<<(N + 39) / 40, 128, 0, stream>>>(prebn, stats, N);
    bn_apply_frag_kernel<<<(N / 16), 256, 0, stream>>>(
        prebn, stats, g0, be0, fused0 + 1024, 1152, l0f, N);

    // layer1: one fused transposed GEMM  [xl | xr]
    {
        dim3 g((N + 255) / 256, 1024 / 128);
        gemm_nt<<<g, 256, 0, stream>>>(l0f, Ap1, bias1f, fused1, N, 1024, K1);
    }
    gat_edge_kernel<<<N, 64, 0, stream>>>(offsets, csr_src, fused1, 1024, att1, b1, prebn, N);
    bn_stats_kernel<<<(N + 39) / 40, 128, 0, stream>>>(prebn, stats + 256, N);
    bn_apply1_kernel<<<(N * 16 + 255) / 256, 256, 0, stream>>>(
        prebn, stats + 256, g1, be1, outf, N);
}

// Round 16
// 276.330 us; speedup vs baseline: 1.0848x; 1.0848x over previous
//
#include <hip/hip_runtime.h>
#include <math.h>

// N=20000 nodes, E=320000 edges (+N self loops), H=4 heads, HID=128, HC=512
#define NEG 0.2f
#define BN_EPS 1e-5f
#define LOG2E 1.44269504088896340736f

typedef __attribute__((ext_vector_type(8))) short  bf16x8;
typedef __attribute__((ext_vector_type(4))) float  f32x4;

__device__ inline unsigned short f2b(float f) {
    unsigned int u = __float_as_uint(f);
    unsigned int r = (u + 0x7fffu + ((u >> 16) & 1u)) >> 16;
    return (unsigned short)r;
}
__device__ inline float b2f_lo(unsigned int u) { return __uint_as_float(u << 16); }
__device__ inline float b2f_hi(unsigned int u) { return __uint_as_float(u & 0xffff0000u); }

__device__ inline unsigned int cvt_pk_bf16(float lo, float hi) {
    unsigned int r;
    asm("v_cvt_pk_bf16_f32 %0, %1, %2" : "=v"(r) : "v"(lo), "v"(hi));
    return r;
}

template<int CTRL>
__device__ inline float dpp_add(float x) {
    int y = __builtin_amdgcn_update_dpp(0, __float_as_int(x), CTRL, 0xF, 0xF, true);
    return x + __int_as_float(y);
}

// ---------------- CSR build ----------------
// per-block (1024) local exclusive scan of (counts[i]+1) + block totals
__global__ void pscan_kernel(const int* __restrict__ counts, int* __restrict__ offsets,
                             int* __restrict__ btot, int n) {
    __shared__ int wsums[16];
    int tid = threadIdx.x, wid = tid >> 6, lane = tid & 63;
    int i = blockIdx.x * 1024 + tid;
    int v = (i < n) ? counts[i] + 1 : 0;   // +1 = self loop
    int incl = v;
#pragma unroll
    for (int off = 1; off < 64; off <<= 1) {
        int t = __shfl_up(incl, off);
        if (lane >= off) incl += t;
    }
    if (lane == 63) wsums[wid] = incl;
    __syncthreads();
    if (tid < 16) {
        int wv = wsums[tid];
        int winc = wv;
#pragma unroll
        for (int off = 1; off < 16; off <<= 1) {
            int t = __shfl_up(winc, off);
            if (tid >= off) winc += t;
        }
        wsums[tid] = winc - wv;
        if (tid == 15) btot[blockIdx.x] = winc;
    }
    __syncthreads();
    if (i < n) offsets[i] = wsums[wid] + incl - v;
}

__global__ void addb_kernel(int* __restrict__ offsets, const int* __restrict__ btot,
                            int n, int nb) {
    __shared__ int sbase;
    if (threadIdx.x == 0) {
        int b = 0, t = 0;
        for (int j = 0; j < nb; ++j) {
            int v = btot[j];
            if (j < (int)blockIdx.x) b += v;
            t += v;
        }
        sbase = b;
        if (blockIdx.x == (unsigned)(nb - 1)) offsets[n] = t;
    }
    __syncthreads();
    int i = blockIdx.x * 1024 + threadIdx.x;
    if (i < n) offsets[i] += sbase;
}

__global__ void scatter_kernel(const int* __restrict__ src, const int* __restrict__ dst,
                               const int* __restrict__ offsets, int* __restrict__ cursor,
                               int* __restrict__ csr_src, int E, int N) {
    int i = blockIdx.x * 256 + threadIdx.x;
    if (i < E) {
        int d = dst[i];
        int pos = offsets[d] + 1 + atomicAdd(&cursor[d], 1);
        csr_src[pos] = src[i];
    } else if (i < E + N) {
        int n = i - E;
        csr_src[offsets[n]] = n;   // self loop at slot 0
    }
}

// ---------------- fused prep: hist + x->B-frag bf16, 5 W^T frag packs, bias concat ----------------
__device__ inline void pack_body(const float* __restrict__ W, unsigned short* __restrict__ Ap,
                                 int K, int Nsrc, int fn_off, int t) {
    int KS = K >> 5;
    int lane = t & 63;
    int frag = t >> 6;
    int ks = frag % KS;
    int nb = frag / KS;
    int fn = fn_off + nb;
    int k0 = ks * 32 + (lane >> 4) * 8;
    int col = nb * 16 + (lane & 15);
    unsigned short o[8];
#pragma unroll
    for (int j = 0; j < 8; ++j) o[j] = f2b(W[(size_t)(k0 + j) * Nsrc + col]);
    *(uint4*)&Ap[(((size_t)fn * KS + ks) * 64 + lane) * 8] = *(uint4*)o;
}

__global__ void prep_kernel(const float* __restrict__ x, unsigned short* __restrict__ xbf,
                            const int* __restrict__ dst, int* __restrict__ counts, int E4,
                            const float* __restrict__ Wl0, const float* __restrict__ Wr0,
                            const float* __restrict__ skW, const float* __restrict__ Wl1,
                            const float* __restrict__ Wr1,
                            unsigned short* __restrict__ Ap0, unsigned short* __restrict__ Ap1,
                            const float* __restrict__ bl0, const float* __restrict__ br0,
                            const float* __restrict__ skb, const float* __restrict__ bl1,
                            const float* __restrict__ br1,
                            float* __restrict__ bias0f, float* __restrict__ bias1f, int N) {
    const int CONV = (N / 16) * 8 / 4;     // 2500 blocks: x -> B-frag layout (K=256, KS=8)
    int b = blockIdx.x, tid = threadIdx.x;
    int wid = tid >> 6, lane = tid & 63;
    if (b < CONV) {
        int wt = b * 4 + wid;              // (ntile, ks)
        int ntile = wt >> 3, ks = wt & 7;
        int r = ntile * 16 + (lane & 15);
        int k = ks * 32 + (lane >> 4) * 8;
        const float4* p = (const float4*)&x[(size_t)r * 256 + k];
        float4 a = p[0], c = p[1];
        unsigned short o[8];
        o[0] = f2b(a.x); o[1] = f2b(a.y); o[2] = f2b(a.z); o[3] = f2b(a.w);
        o[4] = f2b(c.x); o[5] = f2b(c.y); o[6] = f2b(c.z); o[7] = f2b(c.w);
        *(uint4*)&xbf[(((size_t)ntile * 8 + ks) * 64 + lane) * 8] = *(uint4*)o;
        return;
    }
    b -= CONV;
    if (b < 313) {                          // hist (int4-vectorized)
        int i = b * 256 + tid;
        if (i < E4) {
            int4 d = ((const int4*)dst)[i];
            atomicAdd(&counts[d.x], 1);
            atomicAdd(&counts[d.y], 1);
            atomicAdd(&counts[d.z], 1);
            atomicAdd(&counts[d.w], 1);
        }
        return;
    }
    b -= 313;
    if (b < 64)  { pack_body(Wl0, Ap0, 256, 512, 0,  b * 256 + tid); return; }
    b -= 64;
    if (b < 64)  { pack_body(Wr0, Ap0, 256, 512, 32, b * 256 + tid); return; }
    b -= 64;
    if (b < 16)  { pack_body(skW, Ap0, 256, 128, 64, b * 256 + tid); return; }
    b -= 16;
    if (b < 32)  { pack_body(Wl1, Ap1, 128, 512, 0,  b * 256 + tid); return; }
    b -= 32;
    if (b < 32)  { pack_body(Wr1, Ap1, 128, 512, 32, b * 256 + tid); return; }
    b -= 32;
    {
        int i = b * 256 + tid;
        if (i < 1152) {
            float v = (i < 512) ? bl0[i] : (i < 1024 ? br0[i - 512] : skb[i - 1024]);
            bias0f[i] = v;
        } else if (i < 1152 + 1024) {
            int j = i - 1152;
            bias1f[j] = (j < 512) ? bl1[j] : br1[j - 512];
        }
    }
}

// ---------------- transposed MFMA GEMM with XCD-aware swizzle ----------------
// A = W^T frags (Ap), B = node-feature frags (Bf) — both coalesced 1KB loads.
// 1D grid; id = ((gx>>3)*GY + gy)*8 + (gx&7)  =>  all GY ch-blocks of one
// node-slice share id%8 => same XCD (round-robin) => B slice L2-resident.
__global__ __launch_bounds__(256) void gemm_nt(
    const unsigned short* __restrict__ Bf, const unsigned short* __restrict__ Ap,
    const float* __restrict__ bias, unsigned short* __restrict__ out,
    int Mnodes, int Ncols, int K, int GY) {
    int lin = blockIdx.x;
    int lane7 = lin & 7;
    int grp = lin >> 3;
    int gx = (grp / GY) * 8 + lane7;   // node-tile (256 nodes)
    int gy = grp % GY;                 // ch-tile (128 ch)
    if (gx * 256 >= Mnodes + 255 - ((Mnodes + 255) & 255)) { /* no-op guard */ }
    if (gx > (Mnodes - 1) / 256) return;   // pad block

    int wid = threadIdx.x >> 6, lane = threadIdx.x & 63;
    int g = lane >> 4, c15 = lane & 15;
    int cfbase = gy * 8 + (wid & 1) * 4;            // ch-frag base (4 frags = 64 ch)
    int ch0 = cfbase * 16;
    int nodeBase = gx * 256 + (wid >> 1) * 128;     // wave node window (128)
    const int KS = K >> 5;
    const int lastNT = (Mnodes - 1) >> 4;

    f32x4 acc[4][8];
#pragma unroll
    for (int i = 0; i < 4; ++i)
#pragma unroll
        for (int j = 0; j < 8; ++j) acc[i][j] = (f32x4){0.f, 0.f, 0.f, 0.f};

    int nt[8], nd[8];
#pragma unroll
    for (int nf = 0; nf < 8; ++nf) {
        int t = (nodeBase >> 4) + nf;
        nt[nf] = t < lastNT ? t : lastNT;
        nd[nf] = nodeBase + nf * 16 + c15;
    }

    for (int ks = 0; ks < KS; ++ks) {
        bf16x8 a[4];
#pragma unroll
        for (int mf = 0; mf < 4; ++mf)
            a[mf] = *(const bf16x8*)&Ap[(((size_t)(cfbase + mf) * KS + ks) * 64 + lane) * 8];
        bf16x8 b[8];
#pragma unroll
        for (int nf = 0; nf < 8; ++nf)
            b[nf] = *(const bf16x8*)&Bf[(((size_t)nt[nf] * KS + ks) * 64 + lane) * 8];
#pragma unroll
        for (int nf = 0; nf < 8; ++nf)
#pragma unroll
            for (int mf = 0; mf < 4; ++mf)
                acc[mf][nf] = __builtin_amdgcn_mfma_f32_16x16x32_bf16(a[mf], b[nf], acc[mf][nf], 0, 0, 0);
    }
    // epilogue: D row = ch (4 consecutive per lane), col = node
#pragma unroll
    for (int mf = 0; mf < 4; ++mf) {
        int ch = ch0 + mf * 16 + g * 4;
        float4 bs = *(const float4*)&bias[ch];
#pragma unroll
        for (int nf = 0; nf < 8; ++nf) {
            f32x4 v = acc[mf][nf];
            unsigned int p0 = cvt_pk_bf16(v[0] + bs.x, v[1] + bs.y);
            unsigned int p1 = cvt_pk_bf16(v[2] + bs.z, v[3] + bs.w);
            if (nd[nf] < Mnodes)
                *(uint2*)&out[(size_t)nd[nf] * Ncols + ch] = make_uint2(p0, p1);
        }
    }
}

// ---------------- fused edge score + online softmax + aggregate (bf16 features) ----------------
// 1 wave = 1 node = 1 block; depth-8 prefetch; scalarized gather addressing;
// DPP reduce; exp2 domain; bf16 prebn out
__global__ __launch_bounds__(64) void gat_edge_kernel(
    const int* __restrict__ offsets, const int* __restrict__ csr_src,
    const unsigned short* __restrict__ base, int stride,
    const float* __restrict__ att, const float* __restrict__ bvec,
    unsigned short* __restrict__ prebn, int N) {
    int lane = threadIdx.x;
    int n = blockIdx.x;
    if (n >= N) return;
    int start = offsets[n], e1 = offsets[n + 1] - 1;
    float xrv[8], ca[8], cb[8], bv[8];
    {
        uint4 u = *(const uint4*)&base[(size_t)n * stride + 512 + lane * 8];
        xrv[0] = b2f_lo(u.x); xrv[1] = b2f_hi(u.x);
        xrv[2] = b2f_lo(u.y); xrv[3] = b2f_hi(u.y);
        xrv[4] = b2f_lo(u.z); xrv[5] = b2f_hi(u.z);
        xrv[6] = b2f_lo(u.w); xrv[7] = b2f_hi(u.w);
        const float4* q = (const float4*)&att[lane * 8];
        float4 u0 = q[0], u1 = q[1];
        // att*leaky(t) = 0.6*att*t + 0.4*att*|t|, pre-scaled by log2(e) for exp2 softmax
        const float sA = 0.6f * LOG2E, sB = 0.4f * LOG2E;
        ca[0] = u0.x * sA; ca[1] = u0.y * sA; ca[2] = u0.z * sA; ca[3] = u0.w * sA;
        ca[4] = u1.x * sA; ca[5] = u1.y * sA; ca[6] = u1.z * sA; ca[7] = u1.w * sA;
        cb[0] = u0.x * sB; cb[1] = u0.y * sB; cb[2] = u0.z * sB; cb[3] = u0.w * sB;
        cb[4] = u1.x * sB; cb[5] = u1.y * sB; cb[6] = u1.z * sB; cb[7] = u1.w * sB;
        if (lane < 16) {
            const float4* bp = (const float4*)&bvec[lane * 8];
            float4 b0 = bp[0], b1 = bp[1];
            bv[0] = b0.x; bv[1] = b0.y; bv[2] = b0.z; bv[3] = b0.w;
            bv[4] = b1.x; bv[5] = b1.y; bv[6] = b1.z; bv[7] = b1.w;
        }
    }
    float m = -INFINITY, d = 0.f;
    float acc[8] = {0, 0, 0, 0, 0, 0, 0, 0};

    const int lofs = lane * 8;
    auto LD = [&](int j) -> uint4 {
        int jj = j < e1 ? j : e1;
        int s = __builtin_amdgcn_readfirstlane(csr_src[jj]);
        const unsigned short* rowp = base + (size_t)s * stride;
        return *(const uint4*)(rowp + lofs);
    };
    auto PROC = [&](const uint4& Q) {
        float v[8];
        v[0] = b2f_lo(Q.x); v[1] = b2f_hi(Q.x);
        v[2] = b2f_lo(Q.y); v[3] = b2f_hi(Q.y);
        v[4] = b2f_lo(Q.z); v[5] = b2f_hi(Q.z);
        v[6] = b2f_lo(Q.w); v[7] = b2f_hi(Q.w);
        float p = 0.f;
#pragma unroll
        for (int j = 0; j < 8; ++j) {
            float t = v[j] + xrv[j];
            p = fmaf(ca[j], t, fmaf(cb[j], fabsf(t), p));
        }
        p = dpp_add<0xB1>(p);    // quad_perm xor1
        p = dpp_add<0x4E>(p);    // quad_perm xor2
        p = dpp_add<0x141>(p);   // row_half_mirror
        p = dpp_add<0x140>(p);   // row_mirror -> 16-lane sum
        if (__any(p > m)) {
            float mn = fmaxf(m, p);
            float sc = exp2f(m - mn);
            float w = exp2f(p - mn);
            d = fmaf(d, sc, w);
#pragma unroll
            for (int j = 0; j < 8; ++j) acc[j] = fmaf(w, v[j], acc[j] * sc);
            m = mn;
        } else {
            float w = exp2f(p - m);
            d += w;
#pragma unroll
            for (int j = 0; j < 8; ++j) acc[j] = fmaf(w, v[j], acc[j]);
        }
    };

    uint4 q0 = LD(start),     q1 = LD(start + 1), q2 = LD(start + 2), q3 = LD(start + 3),
          q4 = LD(start + 4), q5 = LD(start + 5), q6 = LD(start + 6), q7 = LD(start + 7);
    int i = start;
    for (;;) {
        PROC(q0); if (++i > e1) break; q0 = LD(i + 7);
        PROC(q1); if (++i > e1) break; q1 = LD(i + 7);
        PROC(q2); if (++i > e1) break; q2 = LD(i + 7);
        PROC(q3); if (++i > e1) break; q3 = LD(i + 7);
        PROC(q4); if (++i > e1) break; q4 = LD(i + 7);
        PROC(q5); if (++i > e1) break; q5 = LD(i + 7);
        PROC(q6); if (++i > e1) break; q6 = LD(i + 7);
        PROC(q7); if (++i > e1) break; q7 = LD(i + 7);
    }

    float inv = 1.f / d;
    float t[8];
#pragma unroll
    for (int j = 0; j < 8; ++j) {
        float u = acc[j] * inv;
        u += __shfl_xor(u, 16);    // sum over heads (h bit0)
        u += __shfl_xor(u, 32);    // (h bit1)
        t[j] = u;
    }
    if (lane < 16) {
        float o[8];
#pragma unroll
        for (int j = 0; j < 8; ++j) {
            float v2 = 0.25f * t[j] + bv[j];
            o[j] = v2 > 0.f ? v2 : NEG * v2;   // leaky_relu before BN
        }
        uint4 pk;
        pk.x = cvt_pk_bf16(o[0], o[1]);
        pk.y = cvt_pk_bf16(o[2], o[3]);
        pk.z = cvt_pk_bf16(o[4], o[5]);
        pk.w = cvt_pk_bf16(o[6], o[7]);
        *(uint4*)&prebn[(size_t)n * 128 + lane * 8] = pk;
    }
}

// ---------------- BN stats + apply (bf16 prebn input) ----------------
__global__ void bn_stats_kernel(const unsigned short* __restrict__ v,
                                float* __restrict__ stats, int N) {
    int c = threadIdx.x;  // 128
    int r0 = blockIdx.x * 40;
    int r1 = r0 + 40; if (r1 > N) r1 = N;
    float s = 0.f, ss = 0.f;
    for (int r = r0; r < r1; ++r) {
        float x = b2f_lo((unsigned int)v[(size_t)r * 128 + c]);
        s += x; ss += x * x;
    }
    atomicAdd(&stats[c], s);
    atomicAdd(&stats[128 + c], ss);
}

// layer0 BN apply: write bf16 B-frag layout (feeds gemm1), add strided bf16 skip
__global__ void bn_apply_frag_kernel(const unsigned short* __restrict__ v,
                                     const float* __restrict__ stats,
                                     const float* __restrict__ g, const float* __restrict__ be,
                                     const unsigned short* __restrict__ skip16, int skipStride,
                                     unsigned short* __restrict__ outf, int N) {
    int wid = threadIdx.x >> 6, lane = threadIdx.x & 63;
    int wt = blockIdx.x * 4 + wid;
    int ntile = wt >> 2, ks = wt & 3;
    int r = ntile * 16 + (lane & 15);
    if (r >= N) return;
    int c = ks * 32 + (lane >> 4) * 8;
    float invN = 1.f / (float)N;
    float4 s0 = *(const float4*)&stats[c],       s1 = *(const float4*)&stats[c + 4];
    float4 q0 = *(const float4*)&stats[128 + c], q1 = *(const float4*)&stats[128 + c + 4];
    float4 g0 = *(const float4*)&g[c],  g1 = *(const float4*)&g[c + 4];
    float4 e0 = *(const float4*)&be[c], e1 = *(const float4*)&be[c + 4];
    float mu[8]   = {s0.x, s0.y, s0.z, s0.w, s1.x, s1.y, s1.z, s1.w};
    float ssum[8] = {q0.x, q0.y, q0.z, q0.w, q1.x, q1.y, q1.z, q1.w};
    float gg[8]   = {g0.x, g0.y, g0.z, g0.w, g1.x, g1.y, g1.z, g1.w};
    float ee[8]   = {e0.x, e0.y, e0.z, e0.w, e1.x, e1.y, e1.z, e1.w};
    uint4 xu = *(const uint4*)&v[(size_t)r * 128 + c];
    float xv[8] = {b2f_lo(xu.x), b2f_hi(xu.x), b2f_lo(xu.y), b2f_hi(xu.y),
                   b2f_lo(xu.z), b2f_hi(xu.z), b2f_lo(xu.w), b2f_hi(xu.w)};
    uint4 sk = *(const uint4*)&skip16[(size_t)r * skipStride + c];
    float skf[8] = {b2f_lo(sk.x), b2f_hi(sk.x), b2f_lo(sk.y), b2f_hi(sk.y),
                    b2f_lo(sk.z), b2f_hi(sk.z), b2f_lo(sk.w), b2f_hi(sk.w)};
    unsigned short o[8];
#pragma unroll
    for (int j = 0; j < 8; ++j) {
        float muj = mu[j] * invN;
        float var = ssum[j] * invN - muj * muj;
        float rs = rsqrtf(var + BN_EPS);
        o[j] = f2b((xv[j] - muj) * rs * gg[j] + ee[j] + skf[j]);
    }
    *(uint4*)&outf[(((size_t)ntile * 4 + ks) * 64 + lane) * 8] = *(uint4*)o;
}

// layer1: f32 row-major to d_out
__global__ void bn_apply1_kernel(const unsigned short* __restrict__ v,
                                 const float* __restrict__ stats,
                                 const float* __restrict__ g, const float* __restrict__ be,
                                 float* __restrict__ outf, int N) {
    int t = blockIdx.x * 256 + threadIdx.x;
    if (t >= N * 16) return;
    int node = t >> 4, c = (t & 15) * 8;
    float invN = 1.f / (float)N;
    uint4 xu = *(const uint4*)&v[(size_t)node * 128 + c];
    float xv[8] = {b2f_lo(xu.x), b2f_hi(xu.x), b2f_lo(xu.y), b2f_hi(xu.y),
                   b2f_lo(xu.z), b2f_hi(xu.z), b2f_lo(xu.w), b2f_hi(xu.w)};
    float4 s0 = *(const float4*)&stats[c],       s1 = *(const float4*)&stats[c + 4];
    float4 q0 = *(const float4*)&stats[128 + c], q1 = *(const float4*)&stats[128 + c + 4];
    float4 g0 = *(const float4*)&g[c],  g1 = *(const float4*)&g[c + 4];
    float4 e0 = *(const float4*)&be[c], e1 = *(const float4*)&be[c + 4];
    float mu[8]   = {s0.x, s0.y, s0.z, s0.w, s1.x, s1.y, s1.z, s1.w};
    float ssum[8] = {q0.x, q0.y, q0.z, q0.w, q1.x, q1.y, q1.z, q1.w};
    float gg[8]   = {g0.x, g0.y, g0.z, g0.w, g1.x, g1.y, g1.z, g1.w};
    float ee[8]   = {e0.x, e0.y, e0.z, e0.w, e1.x, e1.y, e1.z, e1.w};
    float o[8];
#pragma unroll
    for (int j = 0; j < 8; ++j) {
        float muj = mu[j] * invN;
        float var = ssum[j] * invN - muj * muj;
        float rs = rsqrtf(var + BN_EPS);
        o[j] = (xv[j] - muj) * rs * gg[j] + ee[j];
    }
    float4* op = (float4*)&outf[(size_t)node * 128 + c];
    op[0] = make_float4(o[0], o[1], o[2], o[3]);
    op[1] = make_float4(o[4], o[5], o[6], o[7]);
}

// ---------------- host ----------------
extern "C" void kernel_launch(void* const* d_in, const int* in_sizes, int n_in,
                              void* d_out, int out_size, void* d_ws, size_t ws_size,
                              hipStream_t stream) {
    const float* x    = (const float*)d_in[0];
    const int*   ei   = (const int*)d_in[1];
    const float* Wl0  = (const float*)d_in[2];
    const float* Wr0  = (const float*)d_in[3];
    const float* bl0  = (const float*)d_in[4];
    const float* br0  = (const float*)d_in[5];
    const float* att0 = (const float*)d_in[6];
    const float* b0   = (const float*)d_in[7];
    const float* g0   = (const float*)d_in[8];
    const float* be0  = (const float*)d_in[9];
    const float* Wl1  = (const float*)d_in[10];
    const float* Wr1  = (const float*)d_in[11];
    const float* bl1  = (const float*)d_in[12];
    const float* br1  = (const float*)d_in[13];
    const float* att1 = (const float*)d_in[14];
    const float* b1   = (const float*)d_in[15];
    const float* g1   = (const float*)d_in[16];
    const float* be1  = (const float*)d_in[17];
    const float* skW  = (const float*)d_in[18];
    const float* skb  = (const float*)d_in[19];

    const int K0 = 256, K1 = 128;
    int N = in_sizes[0] / K0;   // 20000
    int E = in_sizes[1] / 2;    // 320000
    int Etot = E + N;
    int NB = (N + 1023) / 1024; // scan blocks (20)

    // workspace layout (counts|cursor|stats contiguous for one memset)
    char* ws = (char*)d_ws;
    size_t off = 0;
    auto alloc = [&](size_t bytes) { size_t r = off; off += (bytes + 255) & ~(size_t)255; return r; };
    size_t z0 = off;
    int*   counts  = (int*)(ws + alloc((size_t)N * 4));
    int*   cursor  = (int*)(ws + alloc((size_t)N * 4));
    float* stats   = (float*)(ws + alloc(512 * 4));
    size_t z1 = off;
    int*   offsets = (int*)(ws + alloc((size_t)(N + 1) * 4));
    int*   csr_src = (int*)(ws + alloc((size_t)Etot * 4));
    int*   btot    = (int*)(ws + alloc((size_t)NB * 4));
    unsigned short* xbf   = (unsigned short*)(ws + alloc((size_t)N * 256 * 2));   // B-frag layout
    unsigned short* l0f   = (unsigned short*)(ws + alloc((size_t)N * 128 * 2));   // B-frag layout
    unsigned short* prebn = (unsigned short*)(ws + alloc((size_t)N * 128 * 2));   // bf16
    unsigned short* fused0 = (unsigned short*)(ws + alloc((size_t)N * 1152 * 2)); // [xl|xr|skip]
    unsigned short* fused1 = fused0;                                              // alias
    unsigned short* Ap0 = (unsigned short*)(ws + alloc((size_t)(1152 / 16) * (K0 / 32) * 64 * 8 * 2));
    unsigned short* Ap1 = (unsigned short*)(ws + alloc((size_t)(1024 / 16) * (K1 / 32) * 64 * 8 * 2));
    float* bias0f = (float*)(ws + alloc(1152 * 4));
    float* bias1f = (float*)(ws + alloc(1024 * 4));
    float* outf = (float*)d_out;

    const int* src = ei;        // edge_index[0]
    const int* dst = ei + E;    // edge_index[1]

    // zero counts/cursor/stats in one shot
    hipMemsetAsync(ws + z0, 0, z1 - z0, stream);

    // fused prep: conv(B-frag) + hist + 5 packs + bias concat
    {
        int CONV = (N / 16) * 8 / 4;   // 2500
        int nblk = CONV + 313 + 64 + 64 + 16 + 32 + 32 + 9;
        prep_kernel<<<nblk, 256, 0, stream>>>(x, xbf, dst, counts, E / 4,
                                              Wl0, Wr0, skW, Wl1, Wr1, Ap0, Ap1,
                                              bl0, br0, skb, bl1, br1, bias0f, bias1f, N);
    }
    // CSR build (scan depends on hist inside prep)
    pscan_kernel<<<NB, 1024, 0, stream>>>(counts, offsets, btot, N);
    addb_kernel<<<NB, 1024, 0, stream>>>(offsets, btot, N, NB);
    scatter_kernel<<<(Etot + 255) / 256, 256, 0, stream>>>(src, dst, offsets, cursor, csr_src, E, N);

    // XCD-swizzled grids: GXp = node-tiles padded to multiple of 8
    int GXv = (N + 255) / 256;          // 79
    int GXp = (GXv + 7) & ~7;           // 80

    // layer0: one fused transposed GEMM  [xl | xr | skip]
    {
        int GY = 1152 / 128;            // 9
        gemm_nt<<<(GXp / 8) * GY * 8, 256, 0, stream>>>(xbf, Ap0, bias0f, fused0, N, 1152, K0, GY);
    }
    gat_edge_kernel<<<N, 64, 0, stream>>>(offsets, csr_src, fused0, 1152, att0, b0, prebn, N);
    bn_stats_kernel<<<(N + 39) / 40, 128, 0, stream>>>(prebn, stats, N);
    bn_apply_frag_kernel<<<(N / 16), 256, 0, stream>>>(
        prebn, stats, g0, be0, fused0 + 1024, 1152, l0f, N);

    // layer1: one fused transposed GEMM  [xl | xr]
    {
        int GY = 1024 / 128;            // 8
        gemm_nt<<<(GXp / 8) * GY * 8, 256, 0, stream>>>(l0f, Ap1, bias1f, fused1, N, 1024, K1, GY);
    }
    gat_edge_kernel<<<N, 64, 0, stream>>>(offsets, csr_src, fused1, 1024, att1, b1, prebn, N);
    bn_stats_kernel<<<(N + 39) / 40, 128, 0, stream>>>(prebn, stats + 256, N);
    bn_apply1_kernel<<<(N * 16 + 255) / 256, 256, 0, stream>>>(
        prebn, stats + 256, g1, be1, outf, N);
}

// Round 17
// 255.170 us; speedup vs baseline: 1.1747x; 1.0829x over previous
//
#include <hip/hip_runtime.h>
#include <math.h>

// N=20000 nodes, E=320000 edges (+N self loops), H=4 heads, HID=128, HC=512
#define NEG 0.2f
#define BN_EPS 1e-5f
#define LOG2E 1.44269504088896340736f

typedef __attribute__((ext_vector_type(8))) short  bf16x8;
typedef __attribute__((ext_vector_type(4))) float  f32x4;

__device__ inline unsigned short f2b(float f) {
    unsigned int u = __float_as_uint(f);
    unsigned int r = (u + 0x7fffu + ((u >> 16) & 1u)) >> 16;
    return (unsigned short)r;
}
__device__ inline float b2f_lo(unsigned int u) { return __uint_as_float(u << 16); }
__device__ inline float b2f_hi(unsigned int u) { return __uint_as_float(u & 0xffff0000u); }

__device__ inline unsigned int cvt_pk_bf16(float lo, float hi) {
    unsigned int r;
    asm("v_cvt_pk_bf16_f32 %0, %1, %2" : "=v"(r) : "v"(lo), "v"(hi));
    return r;
}

template<int CTRL>
__device__ inline float dpp_add(float x) {
    int y = __builtin_amdgcn_update_dpp(0, __float_as_int(x), CTRL, 0xF, 0xF, true);
    return x + __int_as_float(y);
}

// ---------------- CSR build ----------------
// per-block (1024) local exclusive scan of (counts[i]+1) + block totals
__global__ void pscan_kernel(const int* __restrict__ counts, int* __restrict__ offsets,
                             int* __restrict__ btot, int n) {
    __shared__ int wsums[16];
    int tid = threadIdx.x, wid = tid >> 6, lane = tid & 63;
    int i = blockIdx.x * 1024 + tid;
    int v = (i < n) ? counts[i] + 1 : 0;   // +1 = self loop
    int incl = v;
#pragma unroll
    for (int off = 1; off < 64; off <<= 1) {
        int t = __shfl_up(incl, off);
        if (lane >= off) incl += t;
    }
    if (lane == 63) wsums[wid] = incl;
    __syncthreads();
    if (tid < 16) {
        int wv = wsums[tid];
        int winc = wv;
#pragma unroll
        for (int off = 1; off < 16; off <<= 1) {
            int t = __shfl_up(winc, off);
            if (tid >= off) winc += t;
        }
        wsums[tid] = winc - wv;
        if (tid == 15) btot[blockIdx.x] = winc;
    }
    __syncthreads();
    if (i < n) offsets[i] = wsums[wid] + incl - v;
}

__global__ void addb_kernel(int* __restrict__ offsets, const int* __restrict__ btot,
                            int n, int nb) {
    __shared__ int sbase;
    if (threadIdx.x == 0) {
        int b = 0, t = 0;
        for (int j = 0; j < nb; ++j) {
            int v = btot[j];
            if (j < (int)blockIdx.x) b += v;
            t += v;
        }
        sbase = b;
        if (blockIdx.x == (unsigned)(nb - 1)) offsets[n] = t;
    }
    __syncthreads();
    int i = blockIdx.x * 1024 + threadIdx.x;
    if (i < n) offsets[i] += sbase;
}

__global__ void scatter_kernel(const int* __restrict__ src, const int* __restrict__ dst,
                               const int* __restrict__ offsets, int* __restrict__ cursor,
                               int* __restrict__ csr_src, int E, int N) {
    int i = blockIdx.x * 256 + threadIdx.x;
    if (i < E) {
        int d = dst[i];
        int pos = offsets[d] + 1 + atomicAdd(&cursor[d], 1);
        csr_src[pos] = src[i];
    } else if (i < E + N) {
        int n = i - E;
        csr_src[offsets[n]] = n;   // self loop at slot 0
    }
}

// ---------------- fused prep: hist + x->B-frag bf16, 5 W^T frag packs, bias concat ----------------
__device__ inline void pack_body(const float* __restrict__ W, unsigned short* __restrict__ Ap,
                                 int K, int Nsrc, int fn_off, int t) {
    int KS = K >> 5;
    int lane = t & 63;
    int frag = t >> 6;
    int ks = frag % KS;
    int nb = frag / KS;
    int fn = fn_off + nb;
    int k0 = ks * 32 + (lane >> 4) * 8;
    int col = nb * 16 + (lane & 15);
    unsigned short o[8];
#pragma unroll
    for (int j = 0; j < 8; ++j) o[j] = f2b(W[(size_t)(k0 + j) * Nsrc + col]);
    *(uint4*)&Ap[(((size_t)fn * KS + ks) * 64 + lane) * 8] = *(uint4*)o;
}

__global__ void prep_kernel(const float* __restrict__ x, unsigned short* __restrict__ xbf,
                            const int* __restrict__ dst, int* __restrict__ counts, int E4,
                            const float* __restrict__ Wl0, const float* __restrict__ Wr0,
                            const float* __restrict__ skW, const float* __restrict__ Wl1,
                            const float* __restrict__ Wr1,
                            unsigned short* __restrict__ Ap0, unsigned short* __restrict__ Ap1,
                            const float* __restrict__ bl0, const float* __restrict__ br0,
                            const float* __restrict__ skb, const float* __restrict__ bl1,
                            const float* __restrict__ br1,
                            float* __restrict__ bias0f, float* __restrict__ bias1f, int N) {
    const int CONV = (N / 16) * 8 / 4;     // 2500 blocks: x -> B-frag layout (K=256, KS=8)
    int b = blockIdx.x, tid = threadIdx.x;
    int wid = tid >> 6, lane = tid & 63;
    if (b < CONV) {
        int wt = b * 4 + wid;              // (ntile, ks)
        int ntile = wt >> 3, ks = wt & 7;
        int r = ntile * 16 + (lane & 15);
        int k = ks * 32 + (lane >> 4) * 8;
        const float4* p = (const float4*)&x[(size_t)r * 256 + k];
        float4 a = p[0], c = p[1];
        unsigned short o[8];
        o[0] = f2b(a.x); o[1] = f2b(a.y); o[2] = f2b(a.z); o[3] = f2b(a.w);
        o[4] = f2b(c.x); o[5] = f2b(c.y); o[6] = f2b(c.z); o[7] = f2b(c.w);
        *(uint4*)&xbf[(((size_t)ntile * 8 + ks) * 64 + lane) * 8] = *(uint4*)o;
        return;
    }
    b -= CONV;
    if (b < 313) {                          // hist (int4-vectorized)
        int i = b * 256 + tid;
        if (i < E4) {
            int4 d = ((const int4*)dst)[i];
            atomicAdd(&counts[d.x], 1);
            atomicAdd(&counts[d.y], 1);
            atomicAdd(&counts[d.z], 1);
            atomicAdd(&counts[d.w], 1);
        }
        return;
    }
    b -= 313;
    if (b < 64)  { pack_body(Wl0, Ap0, 256, 512, 0,  b * 256 + tid); return; }
    b -= 64;
    if (b < 64)  { pack_body(Wr0, Ap0, 256, 512, 32, b * 256 + tid); return; }
    b -= 64;
    if (b < 16)  { pack_body(skW, Ap0, 256, 128, 64, b * 256 + tid); return; }
    b -= 16;
    if (b < 32)  { pack_body(Wl1, Ap1, 128, 512, 0,  b * 256 + tid); return; }
    b -= 32;
    if (b < 32)  { pack_body(Wr1, Ap1, 128, 512, 32, b * 256 + tid); return; }
    b -= 32;
    {
        int i = b * 256 + tid;
        if (i < 1152) {
            float v = (i < 512) ? bl0[i] : (i < 1024 ? br0[i - 512] : skb[i - 1024]);
            bias0f[i] = v;
        } else if (i < 1152 + 1024) {
            int j = i - 1152;
            bias1f[j] = (j < 512) ? bl1[j] : br1[j - 512];
        }
    }
}

// ---------------- transposed MFMA GEMM, 128x128 blocks, XCD-aware swizzle ----------------
// A = W^T frags (Ap), B = node-feature frags (Bf) — both coalesced 1KB loads.
// Block = 128 nodes x 128 ch; wave = 64 nodes x 64 ch (acc 4x4). Grid 1D swizzled:
// id = ((gx>>3)*GY + gy)*8 + (gx&7) => ch-blocks of one node-slice share XCD.
__global__ __launch_bounds__(256) void gemm_nt(
    const unsigned short* __restrict__ Bf, const unsigned short* __restrict__ Ap,
    const float* __restrict__ bias, unsigned short* __restrict__ out,
    int Mnodes, int Ncols, int K, int GY, int GXv) {
    int lin = blockIdx.x;
    int lane7 = lin & 7;
    int grp = lin >> 3;
    int gx = (grp / GY) * 8 + lane7;   // node-tile (128 nodes)
    int gy = grp % GY;                 // ch-tile (128 ch)
    if (gx >= GXv) return;             // pad block

    int wid = threadIdx.x >> 6, lane = threadIdx.x & 63;
    int g = lane >> 4, c15 = lane & 15;
    int cfbase = gy * 8 + (wid & 1) * 4;            // 4 ch-frags = 64 ch
    int ch0 = cfbase * 16;
    int nodeBase = gx * 128 + (wid >> 1) * 64;      // wave node window (64)
    const int KS = K >> 5;
    const int lastNT = (Mnodes - 1) >> 4;

    f32x4 acc[4][4];
#pragma unroll
    for (int i = 0; i < 4; ++i)
#pragma unroll
        for (int j = 0; j < 4; ++j) acc[i][j] = (f32x4){0.f, 0.f, 0.f, 0.f};

    int nt[4], nd[4];
#pragma unroll
    for (int nf = 0; nf < 4; ++nf) {
        int t = (nodeBase >> 4) + nf;
        nt[nf] = t < lastNT ? t : lastNT;
        nd[nf] = nodeBase + nf * 16 + c15;
    }

    for (int ks = 0; ks < KS; ++ks) {
        bf16x8 a[4];
#pragma unroll
        for (int mf = 0; mf < 4; ++mf)
            a[mf] = *(const bf16x8*)&Ap[(((size_t)(cfbase + mf) * KS + ks) * 64 + lane) * 8];
        bf16x8 b[4];
#pragma unroll
        for (int nf = 0; nf < 4; ++nf)
            b[nf] = *(const bf16x8*)&Bf[(((size_t)nt[nf] * KS + ks) * 64 + lane) * 8];
#pragma unroll
        for (int nf = 0; nf < 4; ++nf)
#pragma unroll
            for (int mf = 0; mf < 4; ++mf)
                acc[mf][nf] = __builtin_amdgcn_mfma_f32_16x16x32_bf16(a[mf], b[nf], acc[mf][nf], 0, 0, 0);
    }
    // epilogue: D row = ch (4 consecutive per lane), col = node
#pragma unroll
    for (int mf = 0; mf < 4; ++mf) {
        int ch = ch0 + mf * 16 + g * 4;
        float4 bs = *(const float4*)&bias[ch];
#pragma unroll
        for (int nf = 0; nf < 4; ++nf) {
            f32x4 v = acc[mf][nf];
            unsigned int p0 = cvt_pk_bf16(v[0] + bs.x, v[1] + bs.y);
            unsigned int p1 = cvt_pk_bf16(v[2] + bs.z, v[3] + bs.w);
            if (nd[nf] < Mnodes)
                *(uint2*)&out[(size_t)nd[nf] * Ncols + ch] = make_uint2(p0, p1);
        }
    }
}

// ---------------- fused edge score + online softmax + aggregate (bf16 features) ----------------
// 1 wave = 1 node = 1 block; depth-8 prefetch; scalarized gather addressing;
// DPP reduce; exp2 domain; bf16 prebn out
__global__ __launch_bounds__(64) void gat_edge_kernel(
    const int* __restrict__ offsets, const int* __restrict__ csr_src,
    const unsigned short* __restrict__ base, int stride,
    const float* __restrict__ att, const float* __restrict__ bvec,
    unsigned short* __restrict__ prebn, int N) {
    int lane = threadIdx.x;
    int n = blockIdx.x;
    if (n >= N) return;
    int start = offsets[n], e1 = offsets[n + 1] - 1;
    float xrv[8], ca[8], cb[8], bv[8];
    {
        uint4 u = *(const uint4*)&base[(size_t)n * stride + 512 + lane * 8];
        xrv[0] = b2f_lo(u.x); xrv[1] = b2f_hi(u.x);
        xrv[2] = b2f_lo(u.y); xrv[3] = b2f_hi(u.y);
        xrv[4] = b2f_lo(u.z); xrv[5] = b2f_hi(u.z);
        xrv[6] = b2f_lo(u.w); xrv[7] = b2f_hi(u.w);
        const float4* q = (const float4*)&att[lane * 8];
        float4 u0 = q[0], u1 = q[1];
        // att*leaky(t) = 0.6*att*t + 0.4*att*|t|, pre-scaled by log2(e) for exp2 softmax
        const float sA = 0.6f * LOG2E, sB = 0.4f * LOG2E;
        ca[0] = u0.x * sA; ca[1] = u0.y * sA; ca[2] = u0.z * sA; ca[3] = u0.w * sA;
        ca[4] = u1.x * sA; ca[5] = u1.y * sA; ca[6] = u1.z * sA; ca[7] = u1.w * sA;
        cb[0] = u0.x * sB; cb[1] = u0.y * sB; cb[2] = u0.z * sB; cb[3] = u0.w * sB;
        cb[4] = u1.x * sB; cb[5] = u1.y * sB; cb[6] = u1.z * sB; cb[7] = u1.w * sB;
        if (lane < 16) {
            const float4* bp = (const float4*)&bvec[lane * 8];
            float4 b0 = bp[0], b1 = bp[1];
            bv[0] = b0.x; bv[1] = b0.y; bv[2] = b0.z; bv[3] = b0.w;
            bv[4] = b1.x; bv[5] = b1.y; bv[6] = b1.z; bv[7] = b1.w;
        }
    }
    float m = -INFINITY, d = 0.f;
    float acc[8] = {0, 0, 0, 0, 0, 0, 0, 0};

    const int lofs = lane * 8;
    auto LD = [&](int j) -> uint4 {
        int jj = j < e1 ? j : e1;
        int s = __builtin_amdgcn_readfirstlane(csr_src[jj]);
        const unsigned short* rowp = base + (size_t)s * stride;
        return *(const uint4*)(rowp + lofs);
    };
    auto PROC = [&](const uint4& Q) {
        float v[8];
        v[0] = b2f_lo(Q.x); v[1] = b2f_hi(Q.x);
        v[2] = b2f_lo(Q.y); v[3] = b2f_hi(Q.y);
        v[4] = b2f_lo(Q.z); v[5] = b2f_hi(Q.z);
        v[6] = b2f_lo(Q.w); v[7] = b2f_hi(Q.w);
        float p = 0.f;
#pragma unroll
        for (int j = 0; j < 8; ++j) {
            float t = v[j] + xrv[j];
            p = fmaf(ca[j], t, fmaf(cb[j], fabsf(t), p));
        }
        p = dpp_add<0xB1>(p);    // quad_perm xor1
        p = dpp_add<0x4E>(p);    // quad_perm xor2
        p = dpp_add<0x141>(p);   // row_half_mirror
        p = dpp_add<0x140>(p);   // row_mirror -> 16-lane sum
        if (__any(p > m)) {
            float mn = fmaxf(m, p);
            float sc = exp2f(m - mn);
            float w = exp2f(p - mn);
            d = fmaf(d, sc, w);
#pragma unroll
            for (int j = 0; j < 8; ++j) acc[j] = fmaf(w, v[j], acc[j] * sc);
            m = mn;
        } else {
            float w = exp2f(p - m);
            d += w;
#pragma unroll
            for (int j = 0; j < 8; ++j) acc[j] = fmaf(w, v[j], acc[j]);
        }
    };

    uint4 q0 = LD(start),     q1 = LD(start + 1), q2 = LD(start + 2), q3 = LD(start + 3),
          q4 = LD(start + 4), q5 = LD(start + 5), q6 = LD(start + 6), q7 = LD(start + 7);
    int i = start;
    for (;;) {
        PROC(q0); if (++i > e1) break; q0 = LD(i + 7);
        PROC(q1); if (++i > e1) break; q1 = LD(i + 7);
        PROC(q2); if (++i > e1) break; q2 = LD(i + 7);
        PROC(q3); if (++i > e1) break; q3 = LD(i + 7);
        PROC(q4); if (++i > e1) break; q4 = LD(i + 7);
        PROC(q5); if (++i > e1) break; q5 = LD(i + 7);
        PROC(q6); if (++i > e1) break; q6 = LD(i + 7);
        PROC(q7); if (++i > e1) break; q7 = LD(i + 7);
    }

    float inv = 1.f / d;
    float t[8];
#pragma unroll
    for (int j = 0; j < 8; ++j) {
        float u = acc[j] * inv;
        u += __shfl_xor(u, 16);    // sum over heads (h bit0)
        u += __shfl_xor(u, 32);    // (h bit1)
        t[j] = u;
    }
    if (lane < 16) {
        float o[8];
#pragma unroll
        for (int j = 0; j < 8; ++j) {
            float v2 = 0.25f * t[j] + bv[j];
            o[j] = v2 > 0.f ? v2 : NEG * v2;   // leaky_relu before BN
        }
        uint4 pk;
        pk.x = cvt_pk_bf16(o[0], o[1]);
        pk.y = cvt_pk_bf16(o[2], o[3]);
        pk.z = cvt_pk_bf16(o[4], o[5]);
        pk.w = cvt_pk_bf16(o[6], o[7]);
        *(uint4*)&prebn[(size_t)n * 128 + lane * 8] = pk;
    }
}

// ---------------- BN stats + apply (bf16 prebn input) ----------------
__global__ void bn_stats_kernel(const unsigned short* __restrict__ v,
                                float* __restrict__ stats, int N) {
    int c = threadIdx.x;  // 128
    int r0 = blockIdx.x * 40;
    int r1 = r0 + 40; if (r1 > N) r1 = N;
    float s = 0.f, ss = 0.f;
    for (int r = r0; r < r1; ++r) {
        float x = b2f_lo((unsigned int)v[(size_t)r * 128 + c]);
        s += x; ss += x * x;
    }
    atomicAdd(&stats[c], s);
    atomicAdd(&stats[128 + c], ss);
}

// layer0 BN apply: write bf16 B-frag layout (feeds gemm1), add strided bf16 skip
__global__ void bn_apply_frag_kernel(const unsigned short* __restrict__ v,
                                     const float* __restrict__ stats,
                                     const float* __restrict__ g, const float* __restrict__ be,
                                     const unsigned short* __restrict__ skip16, int skipStride,
                                     unsigned short* __restrict__ outf, int N) {
    int wid = threadIdx.x >> 6, lane = threadIdx.x & 63;
    int wt = blockIdx.x * 4 + wid;
    int ntile = wt >> 2, ks = wt & 3;
    int r = ntile * 16 + (lane & 15);
    if (r >= N) return;
    int c = ks * 32 + (lane >> 4) * 8;
    float invN = 1.f / (float)N;
    float4 s0 = *(const float4*)&stats[c],       s1 = *(const float4*)&stats[c + 4];
    float4 q0 = *(const float4*)&stats[128 + c], q1 = *(const float4*)&stats[128 + c + 4];
    float4 g0 = *(const float4*)&g[c],  g1 = *(const float4*)&g[c + 4];
    float4 e0 = *(const float4*)&be[c], e1 = *(const float4*)&be[c + 4];
    float mu[8]   = {s0.x, s0.y, s0.z, s0.w, s1.x, s1.y, s1.z, s1.w};
    float ssum[8] = {q0.x, q0.y, q0.z, q0.w, q1.x, q1.y, q1.z, q1.w};
    float gg[8]   = {g0.x, g0.y, g0.z, g0.w, g1.x, g1.y, g1.z, g1.w};
    float ee[8]   = {e0.x, e0.y, e0.z, e0.w, e1.x, e1.y, e1.z, e1.w};
    uint4 xu = *(const uint4*)&v[(size_t)r * 128 + c];
    float xv[8] = {b2f_lo(xu.x), b2f_hi(xu.x), b2f_lo(xu.y), b2f_hi(xu.y),
                   b2f_lo(xu.z), b2f_hi(xu.z), b2f_lo(xu.w), b2f_hi(xu.w)};
    uint4 sk = *(const uint4*)&skip16[(size_t)r * skipStride + c];
    float skf[8] = {b2f_lo(sk.x), b2f_hi(sk.x), b2f_lo(sk.y), b2f_hi(sk.y),
                    b2f_lo(sk.z), b2f_hi(sk.z), b2f_lo(sk.w), b2f_hi(sk.w)};
    unsigned short o[8];
#pragma unroll
    for (int j = 0; j < 8; ++j) {
        float muj = mu[j] * invN;
        float var = ssum[j] * invN - muj * muj;
        float rs = rsqrtf(var + BN_EPS);
        o[j] = f2b((xv[j] - muj) * rs * gg[j] + ee[j] + skf[j]);
    }
    *(uint4*)&outf[(((size_t)ntile * 4 + ks) * 64 + lane) * 8] = *(uint4*)o;
}

// layer1: f32 row-major to d_out
__global__ void bn_apply1_kernel(const unsigned short* __restrict__ v,
                                 const float* __restrict__ stats,
                                 const float* __restrict__ g, const float* __restrict__ be,
                                 float* __restrict__ outf, int N) {
    int t = blockIdx.x * 256 + threadIdx.x;
    if (t >= N * 16) return;
    int node = t >> 4, c = (t & 15) * 8;
    float invN = 1.f / (float)N;
    uint4 xu = *(const uint4*)&v[(size_t)node * 128 + c];
    float xv[8] = {b2f_lo(xu.x), b2f_hi(xu.x), b2f_lo(xu.y), b2f_hi(xu.y),
                   b2f_lo(xu.z), b2f_hi(xu.z), b2f_lo(xu.w), b2f_hi(xu.w)};
    float4 s0 = *(const float4*)&stats[c],       s1 = *(const float4*)&stats[c + 4];
    float4 q0 = *(const float4*)&stats[128 + c], q1 = *(const float4*)&stats[128 + c + 4];
    float4 g0 = *(const float4*)&g[c],  g1 = *(const float4*)&g[c + 4];
    float4 e0 = *(const float4*)&be[c], e1 = *(const float4*)&be[c + 4];
    float mu[8]   = {s0.x, s0.y, s0.z, s0.w, s1.x, s1.y, s1.z, s1.w};
    float ssum[8] = {q0.x, q0.y, q0.z, q0.w, q1.x, q1.y, q1.z, q1.w};
    float gg[8]   = {g0.x, g0.y, g0.z, g0.w, g1.x, g1.y, g1.z, g1.w};
    float ee[8]   = {e0.x, e0.y, e0.z, e0.w, e1.x, e1.y, e1.z, e1.w};
    float o[8];
#pragma unroll
    for (int j = 0; j < 8; ++j) {
        float muj = mu[j] * invN;
        float var = ssum[j] * invN - muj * muj;
        float rs = rsqrtf(var + BN_EPS);
        o[j] = (xv[j] - muj) * rs * gg[j] + ee[j];
    }
    float4* op = (float4*)&outf[(size_t)node * 128 + c];
    op[0] = make_float4(o[0], o[1], o[2], o[3]);
    op[1] = make_float4(o[4], o[5], o[6], o[7]);
}

// ---------------- host ----------------
extern "C" void kernel_launch(void* const* d_in, const int* in_sizes, int n_in,
                              void* d_out, int out_size, void* d_ws, size_t ws_size,
                              hipStream_t stream) {
    const float* x    = (const float*)d_in[0];
    const int*   ei   = (const int*)d_in[1];
    const float* Wl0  = (const float*)d_in[2];
    const float* Wr0  = (const float*)d_in[3];
    const float* bl0  = (const float*)d_in[4];
    const float* br0  = (const float*)d_in[5];
    const float* att0 = (const float*)d_in[6];
    const float* b0   = (const float*)d_in[7];
    const float* g0   = (const float*)d_in[8];
    const float* be0  = (const float*)d_in[9];
    const float* Wl1  = (const float*)d_in[10];
    const float* Wr1  = (const float*)d_in[11];
    const float* bl1  = (const float*)d_in[12];
    const float* br1  = (const float*)d_in[13];
    const float* att1 = (const float*)d_in[14];
    const float* b1   = (const float*)d_in[15];
    const float* g1   = (const float*)d_in[16];
    const float* be1  = (const float*)d_in[17];
    const float* skW  = (const float*)d_in[18];
    const float* skb  = (const float*)d_in[19];

    const int K0 = 256, K1 = 128;
    int N = in_sizes[0] / K0;   // 20000
    int E = in_sizes[1] / 2;    // 320000
    int Etot = E + N;
    int NB = (N + 1023) / 1024; // scan blocks (20)

    // workspace layout (counts|cursor|stats contiguous for one memset)
    char* ws = (char*)d_ws;
    size_t off = 0;
    auto alloc = [&](size_t bytes) { size_t r = off; off += (bytes + 255) & ~(size_t)255; return r; };
    size_t z0 = off;
    int*   counts  = (int*)(ws + alloc((size_t)N * 4));
    int*   cursor  = (int*)(ws + alloc((size_t)N * 4));
    float* stats   = (float*)(ws + alloc(512 * 4));
    size_t z1 = off;
    int*   offsets = (int*)(ws + alloc((size_t)(N + 1) * 4));
    int*   csr_src = (int*)(ws + alloc((size_t)Etot * 4));
    int*   btot    = (int*)(ws + alloc((size_t)NB * 4));
    unsigned short* xbf   = (unsigned short*)(ws + alloc((size_t)N * 256 * 2));   // B-frag layout
    unsigned short* l0f   = (unsigned short*)(ws + alloc((size_t)N * 128 * 2));   // B-frag layout
    unsigned short* prebn = (unsigned short*)(ws + alloc((size_t)N * 128 * 2));   // bf16
    unsigned short* fused0 = (unsigned short*)(ws + alloc((size_t)N * 1152 * 2)); // [xl|xr|skip]
    unsigned short* fused1 = fused0;                                              // alias
    unsigned short* Ap0 = (unsigned short*)(ws + alloc((size_t)(1152 / 16) * (K0 / 32) * 64 * 8 * 2));
    unsigned short* Ap1 = (unsigned short*)(ws + alloc((size_t)(1024 / 16) * (K1 / 32) * 64 * 8 * 2));
    float* bias0f = (float*)(ws + alloc(1152 * 4));
    float* bias1f = (float*)(ws + alloc(1024 * 4));
    float* outf = (float*)d_out;

    const int* src = ei;        // edge_index[0]
    const int* dst = ei + E;    // edge_index[1]

    // zero counts/cursor/stats in one shot
    hipMemsetAsync(ws + z0, 0, z1 - z0, stream);

    // fused prep: conv(B-frag) + hist + 5 packs + bias concat
    {
        int CONV = (N / 16) * 8 / 4;   // 2500
        int nblk = CONV + 313 + 64 + 64 + 16 + 32 + 32 + 9;
        prep_kernel<<<nblk, 256, 0, stream>>>(x, xbf, dst, counts, E / 4,
                                              Wl0, Wr0, skW, Wl1, Wr1, Ap0, Ap1,
                                              bl0, br0, skb, bl1, br1, bias0f, bias1f, N);
    }
    // CSR build (scan depends on hist inside prep)
    pscan_kernel<<<NB, 1024, 0, stream>>>(counts, offsets, btot, N);
    addb_kernel<<<NB, 1024, 0, stream>>>(offsets, btot, N, NB);
    scatter_kernel<<<(Etot + 255) / 256, 256, 0, stream>>>(src, dst, offsets, cursor, csr_src, E, N);

    // XCD-swizzled grids: 128-node tiles padded to multiple of 8
    int GXv = (N + 127) / 128;          // 157
    int GXp = (GXv + 7) & ~7;           // 160

    // layer0: one fused transposed GEMM  [xl | xr | skip]
    {
        int GY = 1152 / 128;            // 9
        gemm_nt<<<(GXp / 8) * GY * 8, 256, 0, stream>>>(xbf, Ap0, bias0f, fused0, N, 1152, K0, GY, GXv);
    }
    gat_edge_kernel<<<N, 64, 0, stream>>>(offsets, csr_src, fused0, 1152, att0, b0, prebn, N);
    bn_stats_kernel<<<(N + 39) / 40, 128, 0, stream>>>(prebn, stats, N);
    bn_apply_frag_kernel<<<(N / 16), 256, 0, stream>>>(
        prebn, stats, g0, be0, fused0 + 1024, 1152, l0f, N);

    // layer1: one fused transposed GEMM  [xl | xr]
    {
        int GY = 1024 / 128;            // 8
        gemm_nt<<<(GXp / 8) * GY * 8, 256, 0, stream>>>(l0f, Ap1, bias1f, fused1, N, 1024, K1, GY, GXv);
    }
    gat_edge_kernel<<<N, 64, 0, stream>>>(offsets, csr_src, fused1, 1024, att1, b1, prebn, N);
    bn_stats_kernel<<<(N + 39) / 40, 128, 0, stream>>>(prebn, stats + 256, N);
    bn_apply1_kernel<<<(N * 16 + 255) / 256, 256, 0, stream>>>(
        prebn, stats + 256, g1, be1, outf, N);
}